// Round 7
// baseline (320.519 us; speedup 1.0000x reference)
//
#include <hip/hip_runtime.h>

#define B_ 256
#define L_ 50
#define D_ 128
#define T_ 4
#define NH 8
#define NV 4
#define TB_ (T_*B_)
#define EPSF 1e-5f

typedef _Float16 h8 __attribute__((ext_vector_type(8)));
typedef float f4 __attribute__((ext_vector_type(4)));

__device__ __forceinline__ float waveSum(float v) {
    #pragma unroll
    for (int o = 32; o > 0; o >>= 1) v += __shfl_down(v, o, 64);
    return v;
}

// element offset of scale i inside y buffer: 1024*8*sum_{i'<i}(50-i')
__device__ __forceinline__ size_t yoff(int i) {
    return (size_t)8192 * (size_t)(50 * i - (i * (i - 1)) / 2);
}

// K0: split conv_h_w fp32 -> fp16 (hi | lo*1024), [i][dk][c=16][d] with
// 16B-granule pre-swizzle (granule gd stored at gd^c); zero-pad dk>i, i>=50.
__global__ __launch_bounds__(256) void k0_wsplit(
        const float* __restrict__ w, _Float16* __restrict__ whl) {
    int dk = blockIdx.x, i = blockIdx.y;
    int t = threadIdx.x;
    int c = t >> 4, gd = t & 15;
    int h = c & 7;
    bool live = (i < 50) && (dk <= i);
    const float* src = w + (((size_t)i * NH + h) * L_ + dk) * D_ + gd * 8;
    h8 o;
    #pragma unroll
    for (int e = 0; e < 8; ++e) {
        float wv = live ? src[e] : 0.f;
        _Float16 hi = (_Float16)wv;
        o[e] = (c < 8) ? hi : (_Float16)((wv - (float)hi) * 1024.f);
    }
    *(h8*)(whl + (((size_t)i * 50 + dk) * 16 + c) * 128 + ((gd ^ c) & 15) * 8) = o;
}

// K1: embedding + LayerNorm + LIF(T=4) -> s16 [T*B][L][D] fp16 PRE-SWIZZLED, smean fp32
__global__ __launch_bounds__(128) void k1_embed_ln_lif(
        const int* __restrict__ item, const float* __restrict__ tab,
        const float* __restrict__ g, const float* __restrict__ be,
        _Float16* __restrict__ s16, float* __restrict__ smean) {
    int bid = blockIdx.x;
    int b = bid / L_, l = bid % L_;
    int d = threadIdx.x;
    int wid = d >> 6, lane = d & 63;
    __shared__ float red[2];
    int it = item[b * L_ + l];
    float e = tab[(size_t)it * D_ + d];
    float sm_ = waveSum(e);
    if (lane == 0) red[wid] = sm_;
    __syncthreads();
    float mu = (red[0] + red[1]) * (1.f / 128.f);
    __syncthreads();
    float df = e - mu;
    float s2 = waveSum(df * df);
    if (lane == 0) red[wid] = s2;
    __syncthreads();
    float var = (red[0] + red[1]) * (1.f / 128.f);
    float x = df / sqrtf(var + EPSF) * g[d] + be[d];
    float v = 0.f, acc = 0.f;
    int pos = (((d >> 3) ^ l) & 15) * 8 + (d & 7);   // pre-swizzled slot
    #pragma unroll
    for (int t = 0; t < T_; ++t) {
        v += (x - v) * 0.5f;
        float sp = (v >= 1.f) ? 1.f : 0.f;
        v *= (1.f - sp);
        s16[((size_t)(t * B_ + b) * L_ + l) * D_ + pos] = (_Float16)sp;
        acc += sp;
    }
    smean[((size_t)b * L_ + l) * D_ + d] = acc * 0.25f;
}

// ---- K2v: unified scale-group conv. 512 threads = 8 waves, 8 tb/block.
// Wave = (tb-quad tq, dc slice dc). acc[4 sc][4 tt][MTG jt].
// Per dk: 4 B-reads + 4*MTG A-reads feed 16*MTG MFMAs (0.375 KB/MFMA @ MTG=2).
// LDS: A 8tb x 12800 = 102400 (linear, pre-swizzled); B 2 x 16KB slots @102400
// (reg-staged double buffer, ONE barrier per dk). K-partials merged across dc at end.
template<int MTG>
__global__ __launch_bounds__(512, 2) void k2v(
        const _Float16* __restrict__ s16, const _Float16* __restrict__ whl,
        float* __restrict__ y, int gbase, int joff) {
    extern __shared__ __align__(16) char lds[];
    char* B0 = lds + 102400;                 // two 16KB slots
    const int tbo = blockIdx.x;              // 8 tb per block
    const int i0 = (gbase + blockIdx.y) * 4;
    const int kmax = (i0 + 4 <= 50) ? (i0 + 4) : 50;
    const int tid = threadIdx.x;
    const int wave = tid >> 6, lane = tid & 63;
    const int tq = wave >> 2;                // tb-quad 0/1
    const int dc = wave & 3;                 // dc slice 0..3
    const int c_ = lane & 15, g = lane >> 4;

    // stage A (linear copy; swizzle baked into s16)
    {
        const float4* src = (const float4*)(s16 + (size_t)tbo * 8 * (L_ * D_));
        float4* dst = (float4*)lds;
        for (int idx = tid; idx < 6400; idx += 512) dst[idx] = src[idx];
    }
    // B: reg-staged double buffer (16KB chunk = 4 scales x 4KB per dk)
    const char* bsrc = (const char*)whl + (size_t)i0 * 50 * 4096;
    const int o0 = tid * 16, o1 = 8192 + tid * 16;
    const char* g0p = bsrc + (size_t)(o0 >> 12) * (50 * 4096) + (o0 & 4095);
    const char* g1p = bsrc + (size_t)(o1 >> 12) * (50 * 4096) + (o1 & 4095);
    float4 n0 = *(const float4*)(g0p);
    float4 n1 = *(const float4*)(g1p);
    __syncthreads();                         // A staged
    *(float4*)(B0 + o0) = n0;
    *(float4*)(B0 + o1) = n1;
    __syncthreads();                         // slot0 ready

    f4 acc[4][4][MTG];
    #pragma unroll
    for (int sc = 0; sc < 4; ++sc)
        #pragma unroll
        for (int tt = 0; tt < 4; ++tt)
            #pragma unroll
            for (int jt = 0; jt < MTG; ++jt) { f4 z = {0.f, 0.f, 0.f, 0.f}; acc[sc][tt][jt] = z; }

    const int boffc = c_ * 256 + ((((dc << 2) + g) ^ c_) & 15) * 16;
    for (int dk = 0; dk < kmax; ++dk) {
        const bool more = (dk + 1 < kmax);
        float4 m0, m1;
        if (more) {                          // issue next-B loads early (T14)
            m0 = *(const float4*)(g0p + (size_t)(dk + 1) * 4096);
            m1 = *(const float4*)(g1p + (size_t)(dk + 1) * 4096);
        }
        __builtin_amdgcn_sched_barrier(0);
        const char* Bs = B0 + (dk & 1) * 16384;
        h8 bf[4];
        #pragma unroll
        for (int sc = 0; sc < 4; ++sc)
            bf[sc] = *(const h8*)(Bs + sc * 4096 + boffc);
        #pragma unroll
        for (int tt = 0; tt < 4; ++tt) {
            const int tbL = tq * 4 + tt;
            #pragma unroll
            for (int jt = 0; jt < MTG; ++jt) {
                int l = (joff + jt) * 16 + c_ + dk; if (l > 49) l = 49;  // OOB rows -> masked j
                h8 a = *(const h8*)(lds + tbL * 12800 + l * 256 +
                                    ((((dc << 2) + g) ^ l) & 15) * 16);
                #pragma unroll
                for (int sc = 0; sc < 4; ++sc)
                    acc[sc][tt][jt] = __builtin_amdgcn_mfma_f32_16x16x32_f16(a, bf[sc], acc[sc][tt][jt], 0, 0, 0);
            }
        }
        if (more) {                          // write-late into the other slot
            char* Bn = B0 + ((dk + 1) & 1) * 16384;
            *(float4*)(Bn + o0) = m0;
            *(float4*)(Bn + o1) = m1;
        }
        __syncthreads();                     // ONE barrier per dk
    }

    // merge K-partials across dc=1..3 into dc=0, per jt part (LDS reuse of A region).
    // row = ((dc-1)*2+tq)*16 + sc*4+tt  in [0,96); 96 x 64 x 16B = 96KB <= 102400.
    f4* mbuf = (f4*)lds;
    #pragma unroll
    for (int jt = 0; jt < MTG; ++jt) {
        __syncthreads();
        if (dc != 0) {
            f4* wp = mbuf + (size_t)(((dc - 1) * 2 + tq) * 16) * 64 + lane;
            #pragma unroll
            for (int sc = 0; sc < 4; ++sc)
                #pragma unroll
                for (int tt = 0; tt < 4; ++tt)
                    wp[(sc * 4 + tt) * 64] = acc[sc][tt][jt];
        }
        __syncthreads();
        if (dc == 0) {
            #pragma unroll
            for (int dd = 0; dd < 3; ++dd) {
                const f4* rp = mbuf + (size_t)((dd * 2 + tq) * 16) * 64 + lane;
                #pragma unroll
                for (int sc = 0; sc < 4; ++sc)
                    #pragma unroll
                    for (int tt = 0; tt < 4; ++tt)
                        acc[sc][tt][jt] += rp[(sc * 4 + tt) * 64];
            }
        }
    }

    if (dc == 0) {
        const bool hiLane = (c_ < 8);
        const int h = c_ & 7;
        #pragma unroll
        for (int sc = 0; sc < 4; ++sc) {
            const int i = i0 + sc;
            const int J = 50 - i;
            if (J <= 0) continue;
            #pragma unroll
            for (int tt = 0; tt < 4; ++tt) {
                const int tb = tbo * 8 + tq * 4 + tt;
                size_t yb = yoff(i) + ((size_t)tb * NH + h) * J;
                #pragma unroll
                for (int jt = 0; jt < MTG; ++jt) {
                    #pragma unroll
                    for (int r = 0; r < 4; ++r) {
                        float lo = __shfl_xor(acc[sc][tt][jt][r], 8, 64);
                        int j = (joff + jt) * 16 + g * 4 + r;
                        if (hiLane && j < J) y[yb + j] = acc[sc][tt][jt][r] + lo * (1.f / 1024.f);
                    }
                }
            }
        }
    }
}

// K3: BN stats, two stage (partial over 128-tb chunks, then final)
__global__ __launch_bounds__(256) void k3_partial(
        const float* __restrict__ y, float* __restrict__ psum) {
    int ih = blockIdx.x, ck = blockIdx.y;
    int i = ih >> 3, h = ih & 7;
    int J = 50 - i;
    size_t yb = yoff(i);
    int tid = threadIdx.x;
    int grp = tid >> 5, sub = tid & 31;
    float sm = 0.f, ss = 0.f;
    for (int tb = ck * 128 + grp; tb < (ck + 1) * 128; tb += 8) {
        const float* row = y + yb + ((size_t)tb * NH + h) * J;
        for (int j = sub; j < J; j += 32) { float v = row[j]; sm += v; ss += v * v; }
    }
    __shared__ float r1[4], r2[4];
    float a = waveSum(sm), b = waveSum(ss);
    int wid = tid >> 6, lane = tid & 63;
    if (lane == 0) { r1[wid] = a; r2[wid] = b; }
    __syncthreads();
    if (tid == 0) {
        psum[((size_t)ih * 8 + ck) * 2]     = r1[0] + r1[1] + r1[2] + r1[3];
        psum[((size_t)ih * 8 + ck) * 2 + 1] = r2[0] + r2[1] + r2[2] + r2[3];
    }
}

__global__ __launch_bounds__(256) void k3_final(
        const float* __restrict__ psum, const float* __restrict__ bng,
        float* __restrict__ statm, float* __restrict__ stats_) {
    int ih = blockIdx.x * 256 + threadIdx.x;
    if (ih >= 400) return;
    float S = 0.f, Q = 0.f;
    for (int ck = 0; ck < 8; ++ck) {
        S += psum[((size_t)ih * 8 + ck) * 2];
        Q += psum[((size_t)ih * 8 + ck) * 2 + 1];
    }
    int i = ih >> 3;
    float cnt = 1024.f * (float)(50 - i);
    float m = S / cnt;
    float var = Q / cnt - m * m; if (var < 0.f) var = 0.f;
    statm[ih] = m;
    stats_[ih] = bng[ih] / sqrtf(var + EPSF);
}

// K4: BN + LIF over t + max-pool over j -> poolsum [B,400]
__global__ __launch_bounds__(512) void k4_bn_lif_pool(
        const float* __restrict__ y, const float* __restrict__ statm,
        const float* __restrict__ stats_, const float* __restrict__ bnb,
        float* __restrict__ ps) {
    int b = blockIdx.x, i = blockIdx.y, J = L_ - i;
    int h = threadIdx.x >> 6, lane = threadIdx.x & 63;
    int ih = i * NH + h;
    float m = statm[ih], sc = stats_[ih], bb = bnb[ih];
    size_t yb = yoff(i);
    bool valid = lane < J;
    float v = 0.f; int cnt = 0;
    #pragma unroll
    for (int t = 0; t < T_; ++t) {
        int tb = t * B_ + b;
        float yn;
        if (valid) {
            float raw = y[yb + ((size_t)tb * NH + h) * J + lane];
            yn = (raw - m) * sc + bb;
        } else yn = -1e30f;
        v += (yn - v) * 0.5f;
        bool sp = (v >= 1.f);
        if (sp) v = 0.f;
        if (__any(sp)) cnt++;
    }
    if (lane == 0) ps[(size_t)b * 400 + ih] = (float)cnt;
}

// K5: fused heads
__global__ __launch_bounds__(128) void k5_final(
        const float* __restrict__ smean, const float* __restrict__ ps,
        const float* __restrict__ convv, const float* __restrict__ fchw,
        const float* __restrict__ fchb, const float* __restrict__ fcvw,
        const float* __restrict__ fcvb, float* __restrict__ out) {
    __shared__ float sm_l[L_ * D_];
    __shared__ float vm[NV * D_];
    __shared__ float ps_l[400];
    int b = blockIdx.x, tid = threadIdx.x;
    for (int idx = tid; idx < L_ * D_; idx += 128) sm_l[idx] = smean[(size_t)b * (L_ * D_) + idx];
    for (int idx = tid; idx < 400; idx += 128) ps_l[idx] = ps[(size_t)b * 400 + idx];
    __syncthreads();
    int d = tid;
    #pragma unroll
    for (int c = 0; c < NV; ++c) {
        float a = 0.f;
        for (int l = 0; l < L_; ++l) a += convv[c * L_ + l] * sm_l[l * D_ + d];
        vm[c * D_ + d] = a;
    }
    __syncthreads();
    float acc = fchb[d] + fcvb[d];
    float ah = 0.f;
    for (int ih = 0; ih < 400; ++ih) ah += ps_l[ih] * fchw[d * 400 + ih];
    acc += ah * 0.25f;
    float av = 0.f;
    for (int cd = 0; cd < NV * D_; ++cd) av += vm[cd] * fcvw[d * (NV * D_) + cd];
    acc += av;
    out[(size_t)b * D_ + d] = acc;
}

extern "C" void kernel_launch(void* const* d_in, const int* in_sizes, int n_in,
                              void* d_out, int out_size, void* d_ws, size_t ws_size,
                              hipStream_t stream) {
    const int*   item  = (const int*)d_in[0];
    const float* tab   = (const float*)d_in[1];
    const float* lng   = (const float*)d_in[2];
    const float* lnb   = (const float*)d_in[3];
    const float* convv = (const float*)d_in[4];
    const float* convh = (const float*)d_in[5];
    const float* bng   = (const float*)d_in[6];
    const float* bnb   = (const float*)d_in[7];
    const float* fchw  = (const float*)d_in[8];
    const float* fchb  = (const float*)d_in[9];
    const float* fcvw  = (const float*)d_in[10];
    const float* fcvb  = (const float*)d_in[11];
    float* out = (float*)d_out;

    char* ws = (char*)d_ws;
    // layout (bytes):
    // s16    @ 0          13,107,200   fp16 spikes, pre-swizzled granules
    // smean  @ 13107200    6,553,600
    // y      @ 19660800   41,779,200
    // whl    @ 61440000   10,649,600   fp16 hi/lo weights [52][50][16][128], zero-padded
    // statm  @ 72089600        1,600
    // stats_ @ 72091200        1,600
    // ps     @ 72092800      409,600
    // psum   @ 72502400       25,600   -> total 72,528,000
    _Float16* s16  = (_Float16*)(ws);
    float* smean   = (float*)(ws + 13107200LL);
    float* y       = (float*)(ws + 19660800LL);
    _Float16* whl  = (_Float16*)(ws + 61440000LL);
    float* statm   = (float*)(ws + 72089600LL);
    float* stats_  = (float*)(ws + 72091200LL);
    float* ps      = (float*)(ws + 72092800LL);
    float* psum    = (float*)(ws + 72502400LL);

    hipFuncSetAttribute(reinterpret_cast<const void*>(&k2v<1>),
        hipFuncAttributeMaxDynamicSharedMemorySize, 135168);
    hipFuncSetAttribute(reinterpret_cast<const void*>(&k2v<2>),
        hipFuncAttributeMaxDynamicSharedMemorySize, 135168);
    hipFuncSetAttribute(reinterpret_cast<const void*>(&k2v<3>),
        hipFuncAttributeMaxDynamicSharedMemorySize, 135168);

    k0_wsplit<<<dim3(50, 52), 256, 0, stream>>>(convh, whl);
    k1_embed_ln_lif<<<B_ * L_, 128, 0, stream>>>(item, tab, lng, lnb, s16, smean);
    k2v<2><<<dim3(128, 1), 512, 135168, stream>>>(s16, whl, y, 0, 0);  // group 0, j 0-31
    k2v<2><<<dim3(128, 1), 512, 135168, stream>>>(s16, whl, y, 0, 2);  // group 0, j 32-63
    k2v<3><<<dim3(128, 4), 512, 135168, stream>>>(s16, whl, y, 1, 0);  // scales 4-19
    k2v<2><<<dim3(128, 4), 512, 135168, stream>>>(s16, whl, y, 5, 0);  // scales 20-35
    k2v<1><<<dim3(128, 4), 512, 135168, stream>>>(s16, whl, y, 9, 0);  // scales 36-49
    k3_partial<<<dim3(400, 8), 256, 0, stream>>>(y, psum);
    k3_final<<<dim3(2, 1), 256, 0, stream>>>(psum, bng, statm, stats_);
    k4_bn_lif_pool<<<dim3(B_, L_), 512, 0, stream>>>(y, statm, stats_, bnb, ps);
    k5_final<<<B_, 128, 0, stream>>>(smean, ps, convv, fchw, fchb, fcvw, fcvb, out);
}

// Round 8
// 320.380 us; speedup vs baseline: 1.0004x; 1.0004x over previous
//
#include <hip/hip_runtime.h>

#define B_ 256
#define L_ 50
#define D_ 128
#define T_ 4
#define NH 8
#define NV 4
#define TB_ (T_*B_)
#define EPSF 1e-5f

typedef _Float16 h8 __attribute__((ext_vector_type(8)));
typedef float f4 __attribute__((ext_vector_type(4)));

__device__ __forceinline__ float waveSum(float v) {
    #pragma unroll
    for (int o = 32; o > 0; o >>= 1) v += __shfl_down(v, o, 64);
    return v;
}

// element offset of scale i inside y buffer: 1024*8*sum_{i'<i}(50-i')
__device__ __forceinline__ size_t yoff(int i) {
    return (size_t)8192 * (size_t)(50 * i - (i * (i - 1)) / 2);
}

// K0: split conv_h_w fp32 -> fp16 (hi | lo*1024), [i][dk][c=16][d] with
// 16B-granule pre-swizzle (granule gd stored at gd^c); zero-pad dk>i, i>=50.
__global__ __launch_bounds__(256) void k0_wsplit(
        const float* __restrict__ w, _Float16* __restrict__ whl) {
    int dk = blockIdx.x, i = blockIdx.y;
    int t = threadIdx.x;
    int c = t >> 4, gd = t & 15;
    int h = c & 7;
    bool live = (i < 50) && (dk <= i);
    const float* src = w + (((size_t)i * NH + h) * L_ + dk) * D_ + gd * 8;
    h8 o;
    #pragma unroll
    for (int e = 0; e < 8; ++e) {
        float wv = live ? src[e] : 0.f;
        _Float16 hi = (_Float16)wv;
        o[e] = (c < 8) ? hi : (_Float16)((wv - (float)hi) * 1024.f);
    }
    *(h8*)(whl + (((size_t)i * 50 + dk) * 16 + c) * 128 + ((gd ^ c) & 15) * 8) = o;
}

// K1: embedding + LayerNorm + LIF(T=4) -> s16 [T*B][L][D] fp16 PRE-SWIZZLED, smean fp32
__global__ __launch_bounds__(128) void k1_embed_ln_lif(
        const int* __restrict__ item, const float* __restrict__ tab,
        const float* __restrict__ g, const float* __restrict__ be,
        _Float16* __restrict__ s16, float* __restrict__ smean) {
    int bid = blockIdx.x;
    int b = bid / L_, l = bid % L_;
    int d = threadIdx.x;
    int wid = d >> 6, lane = d & 63;
    __shared__ float red[2];
    int it = item[b * L_ + l];
    float e = tab[(size_t)it * D_ + d];
    float sm_ = waveSum(e);
    if (lane == 0) red[wid] = sm_;
    __syncthreads();
    float mu = (red[0] + red[1]) * (1.f / 128.f);
    __syncthreads();
    float df = e - mu;
    float s2 = waveSum(df * df);
    if (lane == 0) red[wid] = s2;
    __syncthreads();
    float var = (red[0] + red[1]) * (1.f / 128.f);
    float x = df / sqrtf(var + EPSF) * g[d] + be[d];
    float v = 0.f, acc = 0.f;
    int pos = (((d >> 3) ^ l) & 15) * 8 + (d & 7);   // pre-swizzled slot
    #pragma unroll
    for (int t = 0; t < T_; ++t) {
        v += (x - v) * 0.5f;
        float sp = (v >= 1.f) ? 1.f : 0.f;
        v *= (1.f - sp);
        s16[((size_t)(t * B_ + b) * L_ + l) * D_ + pos] = (_Float16)sp;
        acc += sp;
    }
    smean[((size_t)b * L_ + l) * D_ + d] = acc * 0.25f;
}

// ---- K2w: barrier-free scale-group conv. 512 threads = 8 waves, 8 tb/block.
// Wave = (tb-quad tq, dc slice dc). acc[4 sc][4 tt][MTG jt].
// B-fragments loaded DIRECTLY global->VGPR (L1/L2-resident whl), 1-deep reg
// double-buffer. LDS holds only A (102400 B, staged once) -> NO barrier in the
// K-loop. K-partials merged across dc-waves at the end (one barrier).
template<int MTG>
__global__ __launch_bounds__(512, 2) void k2w(
        const _Float16* __restrict__ s16, const _Float16* __restrict__ whl,
        float* __restrict__ y, int gbase, int joff) {
    extern __shared__ __align__(16) char lds[];
    const int tbo = blockIdx.x;              // 8 tb per block
    const int i0 = (gbase + blockIdx.y) * 4;
    const int kmax = (i0 + 4 <= 50) ? (i0 + 4) : 50;
    const int tid = threadIdx.x;
    const int wave = tid >> 6, lane = tid & 63;
    const int tq = wave >> 2;                // tb-quad 0/1
    const int dc = wave & 3;                 // dc slice 0..3
    const int c_ = lane & 15, g = lane >> 4;

    // stage A (linear copy; swizzle baked into s16)
    {
        const float4* src = (const float4*)(s16 + (size_t)tbo * 8 * (L_ * D_));
        float4* dst = (float4*)lds;
        for (int idx = tid; idx < 6400; idx += 512) dst[idx] = src[idx];
    }

    // per-lane B base: scale (i0+sc), chunk dk, fragment (c_, dc, g)
    const int boffc = c_ * 256 + ((((dc << 2) + g) ^ c_) & 15) * 16;
    const char* gB = (const char*)whl + (size_t)i0 * 204800 + boffc;  // 204800 = 50*4096

    // preload dk=0 B-fragments while A-stage settles
    h8 bf0 = *(const h8*)(gB);
    h8 bf1 = *(const h8*)(gB + 204800);
    h8 bf2 = *(const h8*)(gB + 409600);
    h8 bf3 = *(const h8*)(gB + 614400);
    __syncthreads();                         // A staged (only barrier before merge)

    f4 acc[4][4][MTG];
    #pragma unroll
    for (int sc = 0; sc < 4; ++sc)
        #pragma unroll
        for (int tt = 0; tt < 4; ++tt)
            #pragma unroll
            for (int jt = 0; jt < MTG; ++jt) { f4 z = {0.f, 0.f, 0.f, 0.f}; acc[sc][tt][jt] = z; }

    for (int dk = 0; dk < kmax; ++dk) {
        const bool more = (dk + 1 < kmax);
        h8 bn0, bn1, bn2, bn3;
        if (more) {                          // issue next-dk B loads early
            const char* p = gB + (size_t)(dk + 1) * 4096;
            bn0 = *(const h8*)(p);
            bn1 = *(const h8*)(p + 204800);
            bn2 = *(const h8*)(p + 409600);
            bn3 = *(const h8*)(p + 614400);
        }
        #pragma unroll
        for (int tt = 0; tt < 4; ++tt) {
            const int tbL = tq * 4 + tt;
            #pragma unroll
            for (int jt = 0; jt < MTG; ++jt) {
                int l = (joff + jt) * 16 + c_ + dk; if (l > 49) l = 49;  // OOB -> masked j
                h8 a = *(const h8*)(lds + tbL * 12800 + l * 256 +
                                    ((((dc << 2) + g) ^ l) & 15) * 16);
                acc[0][tt][jt] = __builtin_amdgcn_mfma_f32_16x16x32_f16(a, bf0, acc[0][tt][jt], 0, 0, 0);
                acc[1][tt][jt] = __builtin_amdgcn_mfma_f32_16x16x32_f16(a, bf1, acc[1][tt][jt], 0, 0, 0);
                acc[2][tt][jt] = __builtin_amdgcn_mfma_f32_16x16x32_f16(a, bf2, acc[2][tt][jt], 0, 0, 0);
                acc[3][tt][jt] = __builtin_amdgcn_mfma_f32_16x16x32_f16(a, bf3, acc[3][tt][jt], 0, 0, 0);
            }
        }
        bf0 = bn0; bf1 = bn1; bf2 = bn2; bf3 = bn3;
    }

    // merge K-partials across dc=1..3 into dc=0, per jt part (LDS reuse of A region).
    // row = ((dc-1)*2+tq)*16 + sc*4+tt  in [0,96); 96 x 64 x 16B = 96KB <= 102400.
    f4* mbuf = (f4*)lds;
    #pragma unroll
    for (int jt = 0; jt < MTG; ++jt) {
        __syncthreads();
        if (dc != 0) {
            f4* wp = mbuf + (size_t)(((dc - 1) * 2 + tq) * 16) * 64 + lane;
            #pragma unroll
            for (int sc = 0; sc < 4; ++sc)
                #pragma unroll
                for (int tt = 0; tt < 4; ++tt)
                    wp[(sc * 4 + tt) * 64] = acc[sc][tt][jt];
        }
        __syncthreads();
        if (dc == 0) {
            #pragma unroll
            for (int dd = 0; dd < 3; ++dd) {
                const f4* rp = mbuf + (size_t)((dd * 2 + tq) * 16) * 64 + lane;
                #pragma unroll
                for (int sc = 0; sc < 4; ++sc)
                    #pragma unroll
                    for (int tt = 0; tt < 4; ++tt)
                        acc[sc][tt][jt] += rp[(sc * 4 + tt) * 64];
            }
        }
    }

    if (dc == 0) {
        const bool hiLane = (c_ < 8);
        const int h = c_ & 7;
        #pragma unroll
        for (int sc = 0; sc < 4; ++sc) {
            const int i = i0 + sc;
            const int J = 50 - i;
            if (J <= 0) continue;
            #pragma unroll
            for (int tt = 0; tt < 4; ++tt) {
                const int tb = tbo * 8 + tq * 4 + tt;
                size_t yb = yoff(i) + ((size_t)tb * NH + h) * J;
                #pragma unroll
                for (int jt = 0; jt < MTG; ++jt) {
                    #pragma unroll
                    for (int r = 0; r < 4; ++r) {
                        float lo = __shfl_xor(acc[sc][tt][jt][r], 8, 64);
                        int j = (joff + jt) * 16 + g * 4 + r;
                        if (hiLane && j < J) y[yb + j] = acc[sc][tt][jt][r] + lo * (1.f / 1024.f);
                    }
                }
            }
        }
    }
}

// K3: BN stats, two stage (partial over 128-tb chunks, then final)
__global__ __launch_bounds__(256) void k3_partial(
        const float* __restrict__ y, float* __restrict__ psum) {
    int ih = blockIdx.x, ck = blockIdx.y;
    int i = ih >> 3, h = ih & 7;
    int J = 50 - i;
    size_t yb = yoff(i);
    int tid = threadIdx.x;
    int grp = tid >> 5, sub = tid & 31;
    float sm = 0.f, ss = 0.f;
    for (int tb = ck * 128 + grp; tb < (ck + 1) * 128; tb += 8) {
        const float* row = y + yb + ((size_t)tb * NH + h) * J;
        for (int j = sub; j < J; j += 32) { float v = row[j]; sm += v; ss += v * v; }
    }
    __shared__ float r1[4], r2[4];
    float a = waveSum(sm), b = waveSum(ss);
    int wid = tid >> 6, lane = tid & 63;
    if (lane == 0) { r1[wid] = a; r2[wid] = b; }
    __syncthreads();
    if (tid == 0) {
        psum[((size_t)ih * 8 + ck) * 2]     = r1[0] + r1[1] + r1[2] + r1[3];
        psum[((size_t)ih * 8 + ck) * 2 + 1] = r2[0] + r2[1] + r2[2] + r2[3];
    }
}

__global__ __launch_bounds__(256) void k3_final(
        const float* __restrict__ psum, const float* __restrict__ bng,
        float* __restrict__ statm, float* __restrict__ stats_) {
    int ih = blockIdx.x * 256 + threadIdx.x;
    if (ih >= 400) return;
    float S = 0.f, Q = 0.f;
    for (int ck = 0; ck < 8; ++ck) {
        S += psum[((size_t)ih * 8 + ck) * 2];
        Q += psum[((size_t)ih * 8 + ck) * 2 + 1];
    }
    int i = ih >> 3;
    float cnt = 1024.f * (float)(50 - i);
    float m = S / cnt;
    float var = Q / cnt - m * m; if (var < 0.f) var = 0.f;
    statm[ih] = m;
    stats_[ih] = bng[ih] / sqrtf(var + EPSF);
}

// K4: BN + LIF over t + max-pool over j -> poolsum [B,400]
__global__ __launch_bounds__(512) void k4_bn_lif_pool(
        const float* __restrict__ y, const float* __restrict__ statm,
        const float* __restrict__ stats_, const float* __restrict__ bnb,
        float* __restrict__ ps) {
    int b = blockIdx.x, i = blockIdx.y, J = L_ - i;
    int h = threadIdx.x >> 6, lane = threadIdx.x & 63;
    int ih = i * NH + h;
    float m = statm[ih], sc = stats_[ih], bb = bnb[ih];
    size_t yb = yoff(i);
    bool valid = lane < J;
    float v = 0.f; int cnt = 0;
    #pragma unroll
    for (int t = 0; t < T_; ++t) {
        int tb = t * B_ + b;
        float yn;
        if (valid) {
            float raw = y[yb + ((size_t)tb * NH + h) * J + lane];
            yn = (raw - m) * sc + bb;
        } else yn = -1e30f;
        v += (yn - v) * 0.5f;
        bool sp = (v >= 1.f);
        if (sp) v = 0.f;
        if (__any(sp)) cnt++;
    }
    if (lane == 0) ps[(size_t)b * 400 + ih] = (float)cnt;
}

// K5: fused heads
__global__ __launch_bounds__(128) void k5_final(
        const float* __restrict__ smean, const float* __restrict__ ps,
        const float* __restrict__ convv, const float* __restrict__ fchw,
        const float* __restrict__ fchb, const float* __restrict__ fcvw,
        const float* __restrict__ fcvb, float* __restrict__ out) {
    __shared__ float sm_l[L_ * D_];
    __shared__ float vm[NV * D_];
    __shared__ float ps_l[400];
    int b = blockIdx.x, tid = threadIdx.x;
    for (int idx = tid; idx < L_ * D_; idx += 128) sm_l[idx] = smean[(size_t)b * (L_ * D_) + idx];
    for (int idx = tid; idx < 400; idx += 128) ps_l[idx] = ps[(size_t)b * 400 + idx];
    __syncthreads();
    int d = tid;
    #pragma unroll
    for (int c = 0; c < NV; ++c) {
        float a = 0.f;
        for (int l = 0; l < L_; ++l) a += convv[c * L_ + l] * sm_l[l * D_ + d];
        vm[c * D_ + d] = a;
    }
    __syncthreads();
    float acc = fchb[d] + fcvb[d];
    float ah = 0.f;
    for (int ih = 0; ih < 400; ++ih) ah += ps_l[ih] * fchw[d * 400 + ih];
    acc += ah * 0.25f;
    float av = 0.f;
    for (int cd = 0; cd < NV * D_; ++cd) av += vm[cd] * fcvw[d * (NV * D_) + cd];
    acc += av;
    out[(size_t)b * D_ + d] = acc;
}

extern "C" void kernel_launch(void* const* d_in, const int* in_sizes, int n_in,
                              void* d_out, int out_size, void* d_ws, size_t ws_size,
                              hipStream_t stream) {
    const int*   item  = (const int*)d_in[0];
    const float* tab   = (const float*)d_in[1];
    const float* lng   = (const float*)d_in[2];
    const float* lnb   = (const float*)d_in[3];
    const float* convv = (const float*)d_in[4];
    const float* convh = (const float*)d_in[5];
    const float* bng   = (const float*)d_in[6];
    const float* bnb   = (const float*)d_in[7];
    const float* fchw  = (const float*)d_in[8];
    const float* fchb  = (const float*)d_in[9];
    const float* fcvw  = (const float*)d_in[10];
    const float* fcvb  = (const float*)d_in[11];
    float* out = (float*)d_out;

    char* ws = (char*)d_ws;
    // layout (bytes):
    // s16    @ 0          13,107,200   fp16 spikes, pre-swizzled granules
    // smean  @ 13107200    6,553,600
    // y      @ 19660800   41,779,200
    // whl    @ 61440000   10,649,600   fp16 hi/lo weights [52][50][16][128], zero-padded
    // statm  @ 72089600        1,600
    // stats_ @ 72091200        1,600
    // ps     @ 72092800      409,600
    // psum   @ 72502400       25,600   -> total 72,528,000
    _Float16* s16  = (_Float16*)(ws);
    float* smean   = (float*)(ws + 13107200LL);
    float* y       = (float*)(ws + 19660800LL);
    _Float16* whl  = (_Float16*)(ws + 61440000LL);
    float* statm   = (float*)(ws + 72089600LL);
    float* stats_  = (float*)(ws + 72091200LL);
    float* ps      = (float*)(ws + 72092800LL);
    float* psum    = (float*)(ws + 72502400LL);

    hipFuncSetAttribute(reinterpret_cast<const void*>(&k2w<1>),
        hipFuncAttributeMaxDynamicSharedMemorySize, 102400);
    hipFuncSetAttribute(reinterpret_cast<const void*>(&k2w<2>),
        hipFuncAttributeMaxDynamicSharedMemorySize, 102400);

    k0_wsplit<<<dim3(50, 52), 256, 0, stream>>>(convh, whl);
    k1_embed_ln_lif<<<B_ * L_, 128, 0, stream>>>(item, tab, lng, lnb, s16, smean);
    // scale coverage: group g covers scales 4g..4g+3, J = 50-i, tiles of 16 rows.
    k2w<2><<<dim3(128, 1), 512, 102400, stream>>>(s16, whl, y, 0, 0);  // i 0-3,  j 0-31
    k2w<2><<<dim3(128, 1), 512, 102400, stream>>>(s16, whl, y, 0, 2);  // i 0-3,  j 32-63
    k2w<2><<<dim3(128, 4), 512, 102400, stream>>>(s16, whl, y, 1, 0);  // i 4-19, j 0-31
    k2w<1><<<dim3(128, 4), 512, 102400, stream>>>(s16, whl, y, 1, 2);  // i 4-19, j 32-47
    k2w<2><<<dim3(128, 4), 512, 102400, stream>>>(s16, whl, y, 5, 0);  // i 20-35, j 0-31
    k2w<1><<<dim3(128, 4), 512, 102400, stream>>>(s16, whl, y, 9, 0);  // i 36-49, j 0-15
    k3_partial<<<dim3(400, 8), 256, 0, stream>>>(y, psum);
    k3_final<<<dim3(2, 1), 256, 0, stream>>>(psum, bng, statm, stats_);
    k4_bn_lif_pool<<<dim3(B_, L_), 512, 0, stream>>>(y, statm, stats_, bnb, ps);
    k5_final<<<B_, 128, 0, stream>>>(smean, ps, convv, fchw, fchb, fcvw, fcvb, out);
}

// Round 9
// 311.628 us; speedup vs baseline: 1.0285x; 1.0281x over previous
//
#include <hip/hip_runtime.h>

#define B_ 256
#define L_ 50
#define D_ 128
#define T_ 4
#define NH 8
#define NV 4
#define TB_ (T_*B_)
#define EPSF 1e-5f

typedef _Float16 h8 __attribute__((ext_vector_type(8)));
typedef float f4 __attribute__((ext_vector_type(4)));

__device__ __forceinline__ float waveSum(float v) {
    #pragma unroll
    for (int o = 32; o > 0; o >>= 1) v += __shfl_down(v, o, 64);
    return v;
}

// element offset of scale i inside y buffer: 1024*8*sum_{i'<i}(50-i')
__device__ __forceinline__ size_t yoff(int i) {
    return (size_t)8192 * (size_t)(50 * i - (i * (i - 1)) / 2);
}

// K0: split conv_h_w fp32 -> fp16 (hi | lo*1024), [i][dk][c=16][d] with
// 16B-granule pre-swizzle (granule gd stored at gd^c); zero-pad dk>i, i>=50.
__global__ __launch_bounds__(256) void k0_wsplit(
        const float* __restrict__ w, _Float16* __restrict__ whl) {
    int dk = blockIdx.x, i = blockIdx.y;
    int t = threadIdx.x;
    int c = t >> 4, gd = t & 15;
    int h = c & 7;
    bool live = (i < 50) && (dk <= i);
    const float* src = w + (((size_t)i * NH + h) * L_ + dk) * D_ + gd * 8;
    h8 o;
    #pragma unroll
    for (int e = 0; e < 8; ++e) {
        float wv = live ? src[e] : 0.f;
        _Float16 hi = (_Float16)wv;
        o[e] = (c < 8) ? hi : (_Float16)((wv - (float)hi) * 1024.f);
    }
    *(h8*)(whl + (((size_t)i * 50 + dk) * 16 + c) * 128 + ((gd ^ c) & 15) * 8) = o;
}

// K1: embedding + LayerNorm + LIF(T=4) -> s16 [T*B][L][D] fp16 PRE-SWIZZLED, smean fp32
__global__ __launch_bounds__(128) void k1_embed_ln_lif(
        const int* __restrict__ item, const float* __restrict__ tab,
        const float* __restrict__ g, const float* __restrict__ be,
        _Float16* __restrict__ s16, float* __restrict__ smean) {
    int bid = blockIdx.x;
    int b = bid / L_, l = bid % L_;
    int d = threadIdx.x;
    int wid = d >> 6, lane = d & 63;
    __shared__ float red[2];
    int it = item[b * L_ + l];
    float e = tab[(size_t)it * D_ + d];
    float sm_ = waveSum(e);
    if (lane == 0) red[wid] = sm_;
    __syncthreads();
    float mu = (red[0] + red[1]) * (1.f / 128.f);
    __syncthreads();
    float df = e - mu;
    float s2 = waveSum(df * df);
    if (lane == 0) red[wid] = s2;
    __syncthreads();
    float var = (red[0] + red[1]) * (1.f / 128.f);
    float x = df / sqrtf(var + EPSF) * g[d] + be[d];
    float v = 0.f, acc = 0.f;
    int pos = (((d >> 3) ^ l) & 15) * 8 + (d & 7);   // pre-swizzled slot
    #pragma unroll
    for (int t = 0; t < T_; ++t) {
        v += (x - v) * 0.5f;
        float sp = (v >= 1.f) ? 1.f : 0.f;
        v *= (1.f - sp);
        s16[((size_t)(t * B_ + b) * L_ + l) * D_ + pos] = (_Float16)sp;
        acc += sp;
    }
    smean[((size_t)b * L_ + l) * D_ + d] = acc * 0.25f;
}

// ---- K2x: job-packed scale-group conv. 512 threads = 8 waves, 4 tb/block,
// 2 blocks/CU (51.2KB LDS) -> 4 waves/SIMD. Wave = (tq: 2tb, dc slice).
// acc[4 sc][2 tt][MTG jt]. B direct global->VGPR reg double-buffer; K-loop has
// NO barriers. dc-partials merged via LDS at end.
// mode 0 (MTG=2 jobs): y<2 -> (g=0, joff=2y); else (g=y-1, joff=0)   [10 jobs]
// mode 1 (MTG=1 jobs): y<4 -> (g=y+1, joff=2); else (g=y+5, joff=0)  [8 jobs]
template<int MTG>
__global__ __launch_bounds__(512, 4) void k2x(
        const _Float16* __restrict__ s16, const _Float16* __restrict__ whl,
        float* __restrict__ y, int mode) {
    extern __shared__ __align__(16) char lds[];
    const int tbq = blockIdx.x;              // 4 tb per block
    int grp, joff;
    if (mode == 0) {
        if (blockIdx.y < 2) { grp = 0; joff = 2 * blockIdx.y; }
        else { grp = blockIdx.y - 1; joff = 0; }
    } else {
        if (blockIdx.y < 4) { grp = blockIdx.y + 1; joff = 2; }
        else { grp = blockIdx.y + 5; joff = 0; }
    }
    const int i0 = grp * 4;
    const int kmax = (i0 + 4 <= 50) ? (i0 + 4) : 50;
    const int tid = threadIdx.x;
    const int wave = tid >> 6, lane = tid & 63;
    const int tq = wave >> 2;                // tb-pair 0/1 (covers 2 tb)
    const int dc = wave & 3;                 // dc slice 0..3
    const int c_ = lane & 15, g = lane >> 4;

    // stage A: 4 tb x 12800 B (linear copy; swizzle baked into s16)
    {
        const float4* src = (const float4*)(s16 + (size_t)tbq * 4 * (L_ * D_));
        float4* dst = (float4*)lds;
        for (int idx = tid; idx < 3200; idx += 512) dst[idx] = src[idx];
    }

    // per-lane B base: scale (i0+sc), chunk dk, fragment (c_, dc, g)
    const int boffc = c_ * 256 + ((((dc << 2) + g) ^ c_) & 15) * 16;
    const char* gB = (const char*)whl + (size_t)i0 * 204800 + boffc;  // 204800 = 50*4096

    // preload dk=0 B-fragments while A-stage settles
    h8 bf0 = *(const h8*)(gB);
    h8 bf1 = *(const h8*)(gB + 204800);
    h8 bf2 = *(const h8*)(gB + 409600);
    h8 bf3 = *(const h8*)(gB + 614400);
    __syncthreads();                         // A staged

    f4 acc[4][2][MTG];
    #pragma unroll
    for (int sc = 0; sc < 4; ++sc)
        #pragma unroll
        for (int tt = 0; tt < 2; ++tt)
            #pragma unroll
            for (int jt = 0; jt < MTG; ++jt) { f4 z = {0.f, 0.f, 0.f, 0.f}; acc[sc][tt][jt] = z; }

    for (int dk = 0; dk < kmax; ++dk) {
        const bool more = (dk + 1 < kmax);
        h8 bn0, bn1, bn2, bn3;
        if (more) {                          // issue next-dk B loads early
            const char* p = gB + (size_t)(dk + 1) * 4096;
            bn0 = *(const h8*)(p);
            bn1 = *(const h8*)(p + 204800);
            bn2 = *(const h8*)(p + 409600);
            bn3 = *(const h8*)(p + 614400);
        }
        #pragma unroll
        for (int tt = 0; tt < 2; ++tt) {
            const int tbL = tq * 2 + tt;
            #pragma unroll
            for (int jt = 0; jt < MTG; ++jt) {
                int l = (joff + jt) * 16 + c_ + dk; if (l > 49) l = 49;  // OOB -> masked j
                h8 a = *(const h8*)(lds + tbL * 12800 + l * 256 +
                                    ((((dc << 2) + g) ^ l) & 15) * 16);
                acc[0][tt][jt] = __builtin_amdgcn_mfma_f32_16x16x32_f16(a, bf0, acc[0][tt][jt], 0, 0, 0);
                acc[1][tt][jt] = __builtin_amdgcn_mfma_f32_16x16x32_f16(a, bf1, acc[1][tt][jt], 0, 0, 0);
                acc[2][tt][jt] = __builtin_amdgcn_mfma_f32_16x16x32_f16(a, bf2, acc[2][tt][jt], 0, 0, 0);
                acc[3][tt][jt] = __builtin_amdgcn_mfma_f32_16x16x32_f16(a, bf3, acc[3][tt][jt], 0, 0, 0);
            }
        }
        bf0 = bn0; bf1 = bn1; bf2 = bn2; bf3 = bn3;
    }

    // merge K-partials across dc=1..3 into dc=0, per jt part (LDS reuse of A region).
    // row = ((dc-1)*2+tq)*8 + sc*2+tt in [0,48); 48 x 64 x 16B = 49152 <= 51200.
    f4* mbuf = (f4*)lds;
    #pragma unroll
    for (int jt = 0; jt < MTG; ++jt) {
        __syncthreads();
        if (dc != 0) {
            f4* wp = mbuf + (size_t)(((dc - 1) * 2 + tq) * 8) * 64 + lane;
            #pragma unroll
            for (int sc = 0; sc < 4; ++sc)
                #pragma unroll
                for (int tt = 0; tt < 2; ++tt)
                    wp[(sc * 2 + tt) * 64] = acc[sc][tt][jt];
        }
        __syncthreads();
        if (dc == 0) {
            #pragma unroll
            for (int dd = 0; dd < 3; ++dd) {
                const f4* rp = mbuf + (size_t)((dd * 2 + tq) * 8) * 64 + lane;
                #pragma unroll
                for (int sc = 0; sc < 4; ++sc)
                    #pragma unroll
                    for (int tt = 0; tt < 2; ++tt)
                        acc[sc][tt][jt] += rp[(sc * 2 + tt) * 64];
            }
        }
    }

    if (dc == 0) {
        const bool hiLane = (c_ < 8);
        const int h = c_ & 7;
        #pragma unroll
        for (int sc = 0; sc < 4; ++sc) {
            const int i = i0 + sc;
            const int J = 50 - i;
            if (J <= 0) continue;
            #pragma unroll
            for (int tt = 0; tt < 2; ++tt) {
                const int tb = tbq * 4 + tq * 2 + tt;
                size_t yb = yoff(i) + ((size_t)tb * NH + h) * J;
                #pragma unroll
                for (int jt = 0; jt < MTG; ++jt) {
                    #pragma unroll
                    for (int r = 0; r < 4; ++r) {
                        float lo = __shfl_xor(acc[sc][tt][jt][r], 8, 64);
                        int j = (joff + jt) * 16 + g * 4 + r;
                        if (hiLane && j < J) y[yb + j] = acc[sc][tt][jt][r] + lo * (1.f / 1024.f);
                    }
                }
            }
        }
    }
}

// K3: BN stats, two stage (partial over 128-tb chunks, then final)
__global__ __launch_bounds__(256) void k3_partial(
        const float* __restrict__ y, float* __restrict__ psum) {
    int ih = blockIdx.x, ck = blockIdx.y;
    int i = ih >> 3, h = ih & 7;
    int J = 50 - i;
    size_t yb = yoff(i);
    int tid = threadIdx.x;
    int grp = tid >> 5, sub = tid & 31;
    float sm = 0.f, ss = 0.f;
    for (int tb = ck * 128 + grp; tb < (ck + 1) * 128; tb += 8) {
        const float* row = y + yb + ((size_t)tb * NH + h) * J;
        for (int j = sub; j < J; j += 32) { float v = row[j]; sm += v; ss += v * v; }
    }
    __shared__ float r1[4], r2[4];
    float a = waveSum(sm), b = waveSum(ss);
    int wid = tid >> 6, lane = tid & 63;
    if (lane == 0) { r1[wid] = a; r2[wid] = b; }
    __syncthreads();
    if (tid == 0) {
        psum[((size_t)ih * 8 + ck) * 2]     = r1[0] + r1[1] + r1[2] + r1[3];
        psum[((size_t)ih * 8 + ck) * 2 + 1] = r2[0] + r2[1] + r2[2] + r2[3];
    }
}

__global__ __launch_bounds__(256) void k3_final(
        const float* __restrict__ psum, const float* __restrict__ bng,
        float* __restrict__ statm, float* __restrict__ stats_) {
    int ih = blockIdx.x * 256 + threadIdx.x;
    if (ih >= 400) return;
    float S = 0.f, Q = 0.f;
    for (int ck = 0; ck < 8; ++ck) {
        S += psum[((size_t)ih * 8 + ck) * 2];
        Q += psum[((size_t)ih * 8 + ck) * 2 + 1];
    }
    int i = ih >> 3;
    float cnt = 1024.f * (float)(50 - i);
    float m = S / cnt;
    float var = Q / cnt - m * m; if (var < 0.f) var = 0.f;
    statm[ih] = m;
    stats_[ih] = bng[ih] / sqrtf(var + EPSF);
}

// K4: BN + LIF over t + max-pool over j -> poolsum [B,400]
__global__ __launch_bounds__(512) void k4_bn_lif_pool(
        const float* __restrict__ y, const float* __restrict__ statm,
        const float* __restrict__ stats_, const float* __restrict__ bnb,
        float* __restrict__ ps) {
    int b = blockIdx.x, i = blockIdx.y, J = L_ - i;
    int h = threadIdx.x >> 6, lane = threadIdx.x & 63;
    int ih = i * NH + h;
    float m = statm[ih], sc = stats_[ih], bb = bnb[ih];
    size_t yb = yoff(i);
    bool valid = lane < J;
    float v = 0.f; int cnt = 0;
    #pragma unroll
    for (int t = 0; t < T_; ++t) {
        int tb = t * B_ + b;
        float yn;
        if (valid) {
            float raw = y[yb + ((size_t)tb * NH + h) * J + lane];
            yn = (raw - m) * sc + bb;
        } else yn = -1e30f;
        v += (yn - v) * 0.5f;
        bool sp = (v >= 1.f);
        if (sp) v = 0.f;
        if (__any(sp)) cnt++;
    }
    if (lane == 0) ps[(size_t)b * 400 + ih] = (float)cnt;
}

// K5: fused heads
__global__ __launch_bounds__(128) void k5_final(
        const float* __restrict__ smean, const float* __restrict__ ps,
        const float* __restrict__ convv, const float* __restrict__ fchw,
        const float* __restrict__ fchb, const float* __restrict__ fcvw,
        const float* __restrict__ fcvb, float* __restrict__ out) {
    __shared__ float sm_l[L_ * D_];
    __shared__ float vm[NV * D_];
    __shared__ float ps_l[400];
    int b = blockIdx.x, tid = threadIdx.x;
    for (int idx = tid; idx < L_ * D_; idx += 128) sm_l[idx] = smean[(size_t)b * (L_ * D_) + idx];
    for (int idx = tid; idx < 400; idx += 128) ps_l[idx] = ps[(size_t)b * 400 + idx];
    __syncthreads();
    int d = tid;
    #pragma unroll
    for (int c = 0; c < NV; ++c) {
        float a = 0.f;
        for (int l = 0; l < L_; ++l) a += convv[c * L_ + l] * sm_l[l * D_ + d];
        vm[c * D_ + d] = a;
    }
    __syncthreads();
    float acc = fchb[d] + fcvb[d];
    float ah = 0.f;
    for (int ih = 0; ih < 400; ++ih) ah += ps_l[ih] * fchw[d * 400 + ih];
    acc += ah * 0.25f;
    float av = 0.f;
    for (int cd = 0; cd < NV * D_; ++cd) av += vm[cd] * fcvw[d * (NV * D_) + cd];
    acc += av;
    out[(size_t)b * D_ + d] = acc;
}

extern "C" void kernel_launch(void* const* d_in, const int* in_sizes, int n_in,
                              void* d_out, int out_size, void* d_ws, size_t ws_size,
                              hipStream_t stream) {
    const int*   item  = (const int*)d_in[0];
    const float* tab   = (const float*)d_in[1];
    const float* lng   = (const float*)d_in[2];
    const float* lnb   = (const float*)d_in[3];
    const float* convv = (const float*)d_in[4];
    const float* convh = (const float*)d_in[5];
    const float* bng   = (const float*)d_in[6];
    const float* bnb   = (const float*)d_in[7];
    const float* fchw  = (const float*)d_in[8];
    const float* fchb  = (const float*)d_in[9];
    const float* fcvw  = (const float*)d_in[10];
    const float* fcvb  = (const float*)d_in[11];
    float* out = (float*)d_out;

    char* ws = (char*)d_ws;
    // layout (bytes):
    // s16    @ 0          13,107,200   fp16 spikes, pre-swizzled granules
    // smean  @ 13107200    6,553,600
    // y      @ 19660800   41,779,200
    // whl    @ 61440000   10,649,600   fp16 hi/lo weights [52][50][16][128], zero-padded
    // statm  @ 72089600        1,600
    // stats_ @ 72091200        1,600
    // ps     @ 72092800      409,600
    // psum   @ 72502400       25,600   -> total 72,528,000
    _Float16* s16  = (_Float16*)(ws);
    float* smean   = (float*)(ws + 13107200LL);
    float* y       = (float*)(ws + 19660800LL);
    _Float16* whl  = (_Float16*)(ws + 61440000LL);
    float* statm   = (float*)(ws + 72089600LL);
    float* stats_  = (float*)(ws + 72091200LL);
    float* ps      = (float*)(ws + 72092800LL);
    float* psum    = (float*)(ws + 72502400LL);

    k0_wsplit<<<dim3(50, 52), 256, 0, stream>>>(convh, whl);
    k1_embed_ln_lif<<<B_ * L_, 128, 0, stream>>>(item, tab, lng, lnb, s16, smean);
    // Two job-packed launches cover all (scale-group, j-window) pairs:
    // mode 0 (MTG=2): {g0/j0-31, g0/j32-63, g1-4/j0-31, g5-8/j0-31}  -> grid (256,10)
    // mode 1 (MTG=1): {g1-4/j32-47, g9-12/j0-15}                     -> grid (256,8)
    k2x<2><<<dim3(256, 10), 512, 51200, stream>>>(s16, whl, y, 0);
    k2x<1><<<dim3(256, 8), 512, 51200, stream>>>(s16, whl, y, 1);
    k3_partial<<<dim3(400, 8), 256, 0, stream>>>(y, psum);
    k3_final<<<dim3(2, 1), 256, 0, stream>>>(psum, bng, statm, stats_);
    k4_bn_lif_pool<<<dim3(B_, L_), 512, 0, stream>>>(y, statm, stats_, bnb, ps);
    k5_final<<<B_, 128, 0, stream>>>(smean, ps, convv, fchw, fchb, fcvw, fcvb, out);
}

// Round 10
// 303.379 us; speedup vs baseline: 1.0565x; 1.0272x over previous
//
#include <hip/hip_runtime.h>

#define B_ 256
#define L_ 50
#define D_ 128
#define T_ 4
#define NH 8
#define NV 4
#define TB_ (T_*B_)
#define EPSF 1e-5f

typedef _Float16 h8 __attribute__((ext_vector_type(8)));
typedef float f4 __attribute__((ext_vector_type(4)));

__device__ __forceinline__ float waveSum(float v) {
    #pragma unroll
    for (int o = 32; o > 0; o >>= 1) v += __shfl_down(v, o, 64);
    return v;
}

// element offset of scale i inside y buffer: 1024*8*sum_{i'<i}(50-i')
__device__ __forceinline__ size_t yoff(int i) {
    return (size_t)8192 * (size_t)(50 * i - (i * (i - 1)) / 2);
}

// K0: split conv_h_w fp32 -> fp16 (hi | lo*1024), [i][dk][c=16][d] with
// 16B-granule pre-swizzle (granule gd stored at gd^c); zero-pad dk>i, i>=50.
__global__ __launch_bounds__(256) void k0_wsplit(
        const float* __restrict__ w, _Float16* __restrict__ whl) {
    int dk = blockIdx.x, i = blockIdx.y;
    int t = threadIdx.x;
    int c = t >> 4, gd = t & 15;
    int h = c & 7;
    bool live = (i < 50) && (dk <= i);
    const float* src = w + (((size_t)i * NH + h) * L_ + dk) * D_ + gd * 8;
    h8 o;
    #pragma unroll
    for (int e = 0; e < 8; ++e) {
        float wv = live ? src[e] : 0.f;
        _Float16 hi = (_Float16)wv;
        o[e] = (c < 8) ? hi : (_Float16)((wv - (float)hi) * 1024.f);
    }
    *(h8*)(whl + (((size_t)i * 50 + dk) * 16 + c) * 128 + ((gd ^ c) & 15) * 8) = o;
}

// K1: embedding + LayerNorm + LIF(T=4) -> s16 [T*B][L][D] fp16 PRE-SWIZZLED, smean fp32
__global__ __launch_bounds__(128) void k1_embed_ln_lif(
        const int* __restrict__ item, const float* __restrict__ tab,
        const float* __restrict__ g, const float* __restrict__ be,
        _Float16* __restrict__ s16, float* __restrict__ smean) {
    int bid = blockIdx.x;
    int b = bid / L_, l = bid % L_;
    int d = threadIdx.x;
    int wid = d >> 6, lane = d & 63;
    __shared__ float red[2];
    int it = item[b * L_ + l];
    float e = tab[(size_t)it * D_ + d];
    float sm_ = waveSum(e);
    if (lane == 0) red[wid] = sm_;
    __syncthreads();
    float mu = (red[0] + red[1]) * (1.f / 128.f);
    __syncthreads();
    float df = e - mu;
    float s2 = waveSum(df * df);
    if (lane == 0) red[wid] = s2;
    __syncthreads();
    float var = (red[0] + red[1]) * (1.f / 128.f);
    float x = df / sqrtf(var + EPSF) * g[d] + be[d];
    float v = 0.f, acc = 0.f;
    int pos = (((d >> 3) ^ l) & 15) * 8 + (d & 7);   // pre-swizzled slot
    #pragma unroll
    for (int t = 0; t < T_; ++t) {
        v += (x - v) * 0.5f;
        float sp = (v >= 1.f) ? 1.f : 0.f;
        v *= (1.f - sp);
        s16[((size_t)(t * B_ + b) * L_ + l) * D_ + pos] = (_Float16)sp;
        acc += sp;
    }
    smean[((size_t)b * L_ + l) * D_ + d] = acc * 0.25f;
}

// ---- K2m: A-stationary mega conv kernel.
// grid (256 tbq, 2 sg) = 512 blocks = 2 blocks/CU. 512 threads = 8 waves.
// Block stages its 4-tb A-tile ONCE (51.2 KB), then walks a balanced job table
// (job = scale-group i0, j-window joff, width MTG). Per job: k2x's proven
// dk-loop (B global->VGPR double buffer, no barriers, dc-split waves) with
// s_setprio(1) around the MFMA cluster; dc-partials merged through a separate
// 24.6 KB buffer so A persists across jobs. LDS total 75776 B -> 2 blocks/CU.

// job tables: sg0 cost 298, sg1 cost 308 (unit = 64 MFMA/block)
__device__ const int JT_N[2] = {6, 12};
__device__ const int JT_i0[2][12] = {
    {48, 32, 28, 24, 20, 0,  0, 0, 0, 0, 0, 0},
    {16, 16, 12, 12, 8, 8, 4, 4, 36, 40, 44, 0}};
__device__ const int JT_jo[2][12] = {
    {0, 0, 0, 0, 0, 0,  0, 0, 0, 0, 0, 0},
    {0, 2, 0, 2, 0, 2, 0, 2, 0, 0, 0, 2}};
__device__ const int JT_mt[2][12] = {
    {1, 2, 2, 2, 2, 2,  0, 0, 0, 0, 0, 0},
    {2, 1, 2, 1, 2, 1, 2, 1, 1, 1, 1, 2}};

template<int MTG>
__device__ __forceinline__ void k2m_job(
        const char* lds, char* mrg, const _Float16* __restrict__ whl,
        float* __restrict__ y, int i0, int joff,
        int tbq, int tq, int dc, int c_, int g) {
    const int kmax = (i0 + 4 <= 50) ? (i0 + 4) : 50;
    const int boffc = c_ * 256 + ((((dc << 2) + g) ^ c_) & 15) * 16;
    const char* gB = (const char*)whl + (size_t)i0 * 204800 + boffc;  // 204800 = 50*4096

    h8 bf0 = *(const h8*)(gB);
    h8 bf1 = *(const h8*)(gB + 204800);
    h8 bf2 = *(const h8*)(gB + 409600);
    h8 bf3 = *(const h8*)(gB + 614400);

    f4 acc[4][2][MTG];
    #pragma unroll
    for (int sc = 0; sc < 4; ++sc)
        #pragma unroll
        for (int tt = 0; tt < 2; ++tt)
            #pragma unroll
            for (int jt = 0; jt < MTG; ++jt) { f4 z = {0.f, 0.f, 0.f, 0.f}; acc[sc][tt][jt] = z; }

    for (int dk = 0; dk < kmax; ++dk) {
        const bool more = (dk + 1 < kmax);
        h8 bn0, bn1, bn2, bn3;
        if (more) {                          // issue next-dk B loads early
            const char* p = gB + (size_t)(dk + 1) * 4096;
            bn0 = *(const h8*)(p);
            bn1 = *(const h8*)(p + 204800);
            bn2 = *(const h8*)(p + 409600);
            bn3 = *(const h8*)(p + 614400);
        }
        __builtin_amdgcn_s_setprio(1);
        #pragma unroll
        for (int tt = 0; tt < 2; ++tt) {
            const int tbL = tq * 2 + tt;
            #pragma unroll
            for (int jt = 0; jt < MTG; ++jt) {
                int l = (joff + jt) * 16 + c_ + dk; if (l > 49) l = 49;  // OOB -> masked j
                h8 a = *(const h8*)(lds + tbL * 12800 + l * 256 +
                                    ((((dc << 2) + g) ^ l) & 15) * 16);
                acc[0][tt][jt] = __builtin_amdgcn_mfma_f32_16x16x32_f16(a, bf0, acc[0][tt][jt], 0, 0, 0);
                acc[1][tt][jt] = __builtin_amdgcn_mfma_f32_16x16x32_f16(a, bf1, acc[1][tt][jt], 0, 0, 0);
                acc[2][tt][jt] = __builtin_amdgcn_mfma_f32_16x16x32_f16(a, bf2, acc[2][tt][jt], 0, 0, 0);
                acc[3][tt][jt] = __builtin_amdgcn_mfma_f32_16x16x32_f16(a, bf3, acc[3][tt][jt], 0, 0, 0);
            }
        }
        __builtin_amdgcn_s_setprio(0);
        bf0 = bn0; bf1 = bn1; bf2 = bn2; bf3 = bn3;
    }

    // merge dc=1..3 partials into dc=0, per (jt, sc-pair) through mrg buffer.
    // row = ((dc-1)*2+tq)*4 + scl*2+tt in [0,24); 24 x 64 x 16B = 24576 B.
    f4* mbuf = (f4*)mrg;
    const int lane = (threadIdx.x & 63);
    #pragma unroll
    for (int jt = 0; jt < MTG; ++jt) {
        #pragma unroll
        for (int sp = 0; sp < 2; ++sp) {
            __syncthreads();                 // also protects prev job's reads
            if (dc != 0) {
                f4* wp = mbuf + (size_t)(((dc - 1) * 2 + tq) * 4) * 64 + lane;
                #pragma unroll
                for (int scl = 0; scl < 2; ++scl)
                    #pragma unroll
                    for (int tt = 0; tt < 2; ++tt)
                        wp[(scl * 2 + tt) * 64] = acc[sp * 2 + scl][tt][jt];
            }
            __syncthreads();
            if (dc == 0) {
                #pragma unroll
                for (int dd = 0; dd < 3; ++dd) {
                    const f4* rp = mbuf + (size_t)((dd * 2 + tq) * 4) * 64 + lane;
                    #pragma unroll
                    for (int scl = 0; scl < 2; ++scl)
                        #pragma unroll
                        for (int tt = 0; tt < 2; ++tt)
                            acc[sp * 2 + scl][tt][jt] += rp[(scl * 2 + tt) * 64];
                }
            }
        }
    }

    if (dc == 0) {
        const bool hiLane = (c_ < 8);
        const int h = c_ & 7;
        #pragma unroll
        for (int sc = 0; sc < 4; ++sc) {
            const int i = i0 + sc;
            const int J = 50 - i;
            if (J <= 0) continue;
            #pragma unroll
            for (int tt = 0; tt < 2; ++tt) {
                const int tb = tbq * 4 + tq * 2 + tt;
                size_t yb = yoff(i) + ((size_t)tb * NH + h) * J;
                #pragma unroll
                for (int jt = 0; jt < MTG; ++jt) {
                    #pragma unroll
                    for (int r = 0; r < 4; ++r) {
                        float lo = __shfl_xor(acc[sc][tt][jt][r], 8, 64);
                        int j = (joff + jt) * 16 + g * 4 + r;
                        if (hiLane && j < J) y[yb + j] = acc[sc][tt][jt][r] + lo * (1.f / 1024.f);
                    }
                }
            }
        }
    }
}

__global__ __launch_bounds__(512, 4) void k2m(
        const _Float16* __restrict__ s16, const _Float16* __restrict__ whl,
        float* __restrict__ y) {
    extern __shared__ __align__(16) char lds[];
    char* mrg = lds + 51200;
    const int tbq = blockIdx.x;              // 4 tb per block
    const int sg = blockIdx.y;               // scale-half
    const int tid = threadIdx.x;
    const int wave = tid >> 6, lane = tid & 63;
    const int tq = wave >> 2;                // tb-pair 0/1
    const int dc = wave & 3;                 // dc slice 0..3
    const int c_ = lane & 15, g = lane >> 4;

    // stage A once: 4 tb x 12800 B (linear copy; swizzle baked into s16)
    {
        const float4* src = (const float4*)(s16 + (size_t)tbq * 4 * (L_ * D_));
        float4* dst = (float4*)lds;
        for (int idx = tid; idx < 3200; idx += 512) dst[idx] = src[idx];
    }
    __syncthreads();

    const int nj = JT_N[sg];
    for (int jo = 0; jo < nj; ++jo) {
        const int i0 = JT_i0[sg][jo];
        const int joff = JT_jo[sg][jo];
        if (JT_mt[sg][jo] == 2)
            k2m_job<2>(lds, mrg, whl, y, i0, joff, tbq, tq, dc, c_, g);
        else
            k2m_job<1>(lds, mrg, whl, y, i0, joff, tbq, tq, dc, c_, g);
    }
}

// K3: BN stats, two stage (partial over 128-tb chunks, then final)
__global__ __launch_bounds__(256) void k3_partial(
        const float* __restrict__ y, float* __restrict__ psum) {
    int ih = blockIdx.x, ck = blockIdx.y;
    int i = ih >> 3, h = ih & 7;
    int J = 50 - i;
    size_t yb = yoff(i);
    int tid = threadIdx.x;
    int grp = tid >> 5, sub = tid & 31;
    float sm = 0.f, ss = 0.f;
    for (int tb = ck * 128 + grp; tb < (ck + 1) * 128; tb += 8) {
        const float* row = y + yb + ((size_t)tb * NH + h) * J;
        for (int j = sub; j < J; j += 32) { float v = row[j]; sm += v; ss += v * v; }
    }
    __shared__ float r1[4], r2[4];
    float a = waveSum(sm), b = waveSum(ss);
    int wid = tid >> 6, lane = tid & 63;
    if (lane == 0) { r1[wid] = a; r2[wid] = b; }
    __syncthreads();
    if (tid == 0) {
        psum[((size_t)ih * 8 + ck) * 2]     = r1[0] + r1[1] + r1[2] + r1[3];
        psum[((size_t)ih * 8 + ck) * 2 + 1] = r2[0] + r2[1] + r2[2] + r2[3];
    }
}

__global__ __launch_bounds__(256) void k3_final(
        const float* __restrict__ psum, const float* __restrict__ bng,
        float* __restrict__ statm, float* __restrict__ stats_) {
    int ih = blockIdx.x * 256 + threadIdx.x;
    if (ih >= 400) return;
    float S = 0.f, Q = 0.f;
    for (int ck = 0; ck < 8; ++ck) {
        S += psum[((size_t)ih * 8 + ck) * 2];
        Q += psum[((size_t)ih * 8 + ck) * 2 + 1];
    }
    int i = ih >> 3;
    float cnt = 1024.f * (float)(50 - i);
    float m = S / cnt;
    float var = Q / cnt - m * m; if (var < 0.f) var = 0.f;
    statm[ih] = m;
    stats_[ih] = bng[ih] / sqrtf(var + EPSF);
}

// K4: BN + LIF over t + max-pool over j -> poolsum [B,400]
__global__ __launch_bounds__(512) void k4_bn_lif_pool(
        const float* __restrict__ y, const float* __restrict__ statm,
        const float* __restrict__ stats_, const float* __restrict__ bnb,
        float* __restrict__ ps) {
    int b = blockIdx.x, i = blockIdx.y, J = L_ - i;
    int h = threadIdx.x >> 6, lane = threadIdx.x & 63;
    int ih = i * NH + h;
    float m = statm[ih], sc = stats_[ih], bb = bnb[ih];
    size_t yb = yoff(i);
    bool valid = lane < J;
    float v = 0.f; int cnt = 0;
    #pragma unroll
    for (int t = 0; t < T_; ++t) {
        int tb = t * B_ + b;
        float yn;
        if (valid) {
            float raw = y[yb + ((size_t)tb * NH + h) * J + lane];
            yn = (raw - m) * sc + bb;
        } else yn = -1e30f;
        v += (yn - v) * 0.5f;
        bool sp = (v >= 1.f);
        if (sp) v = 0.f;
        if (__any(sp)) cnt++;
    }
    if (lane == 0) ps[(size_t)b * 400 + ih] = (float)cnt;
}

// K5: fused heads
__global__ __launch_bounds__(128) void k5_final(
        const float* __restrict__ smean, const float* __restrict__ ps,
        const float* __restrict__ convv, const float* __restrict__ fchw,
        const float* __restrict__ fchb, const float* __restrict__ fcvw,
        const float* __restrict__ fcvb, float* __restrict__ out) {
    __shared__ float sm_l[L_ * D_];
    __shared__ float vm[NV * D_];
    __shared__ float ps_l[400];
    int b = blockIdx.x, tid = threadIdx.x;
    for (int idx = tid; idx < L_ * D_; idx += 128) sm_l[idx] = smean[(size_t)b * (L_ * D_) + idx];
    for (int idx = tid; idx < 400; idx += 128) ps_l[idx] = ps[(size_t)b * 400 + idx];
    __syncthreads();
    int d = tid;
    #pragma unroll
    for (int c = 0; c < NV; ++c) {
        float a = 0.f;
        for (int l = 0; l < L_; ++l) a += convv[c * L_ + l] * sm_l[l * D_ + d];
        vm[c * D_ + d] = a;
    }
    __syncthreads();
    float acc = fchb[d] + fcvb[d];
    float ah = 0.f;
    for (int ih = 0; ih < 400; ++ih) ah += ps_l[ih] * fchw[d * 400 + ih];
    acc += ah * 0.25f;
    float av = 0.f;
    for (int cd = 0; cd < NV * D_; ++cd) av += vm[cd] * fcvw[d * (NV * D_) + cd];
    acc += av;
    out[(size_t)b * D_ + d] = acc;
}

extern "C" void kernel_launch(void* const* d_in, const int* in_sizes, int n_in,
                              void* d_out, int out_size, void* d_ws, size_t ws_size,
                              hipStream_t stream) {
    const int*   item  = (const int*)d_in[0];
    const float* tab   = (const float*)d_in[1];
    const float* lng   = (const float*)d_in[2];
    const float* lnb   = (const float*)d_in[3];
    const float* convv = (const float*)d_in[4];
    const float* convh = (const float*)d_in[5];
    const float* bng   = (const float*)d_in[6];
    const float* bnb   = (const float*)d_in[7];
    const float* fchw  = (const float*)d_in[8];
    const float* fchb  = (const float*)d_in[9];
    const float* fcvw  = (const float*)d_in[10];
    const float* fcvb  = (const float*)d_in[11];
    float* out = (float*)d_out;

    char* ws = (char*)d_ws;
    // layout (bytes):
    // s16    @ 0          13,107,200   fp16 spikes, pre-swizzled granules
    // smean  @ 13107200    6,553,600
    // y      @ 19660800   41,779,200
    // whl    @ 61440000   10,649,600   fp16 hi/lo weights [52][50][16][128], zero-padded
    // statm  @ 72089600        1,600
    // stats_ @ 72091200        1,600
    // ps     @ 72092800      409,600
    // psum   @ 72502400       25,600   -> total 72,528,000
    _Float16* s16  = (_Float16*)(ws);
    float* smean   = (float*)(ws + 13107200LL);
    float* y       = (float*)(ws + 19660800LL);
    _Float16* whl  = (_Float16*)(ws + 61440000LL);
    float* statm   = (float*)(ws + 72089600LL);
    float* stats_  = (float*)(ws + 72091200LL);
    float* ps      = (float*)(ws + 72092800LL);
    float* psum    = (float*)(ws + 72502400LL);

    hipFuncSetAttribute(reinterpret_cast<const void*>(&k2m),
        hipFuncAttributeMaxDynamicSharedMemorySize, 75776);

    k0_wsplit<<<dim3(50, 52), 256, 0, stream>>>(convh, whl);
    k1_embed_ln_lif<<<B_ * L_, 128, 0, stream>>>(item, tab, lng, lnb, s16, smean);
    k2m<<<dim3(256, 2), 512, 75776, stream>>>(s16, whl, y);
    k3_partial<<<dim3(400, 8), 256, 0, stream>>>(y, psum);
    k3_final<<<dim3(2, 1), 256, 0, stream>>>(psum, bng, statm, stats_);
    k4_bn_lif_pool<<<dim3(B_, L_), 512, 0, stream>>>(y, statm, stats_, bnb, ps);
    k5_final<<<B_, 128, 0, stream>>>(smean, ps, convv, fchw, fchb, fcvw, fcvb, out);
}

// Round 11
// 289.576 us; speedup vs baseline: 1.1069x; 1.0477x over previous
//
#include <hip/hip_runtime.h>

#define B_ 256
#define L_ 50
#define D_ 128
#define T_ 4
#define NH 8
#define NV 4
#define TB_ (T_*B_)
#define EPSF 1e-5f

typedef _Float16 h8 __attribute__((ext_vector_type(8)));
typedef float f4 __attribute__((ext_vector_type(4)));

__device__ __forceinline__ float waveSum(float v) {
    #pragma unroll
    for (int o = 32; o > 0; o >>= 1) v += __shfl_down(v, o, 64);
    return v;
}

// element offset of scale i inside y buffer: 1024*8*sum_{i'<i}(50-i')
__device__ __forceinline__ size_t yoff(int i) {
    return (size_t)8192 * (size_t)(50 * i - (i * (i - 1)) / 2);
}

// K0: split conv_h_w fp32 -> fp16 (hi | lo*1024), [i][dk][c=16][d] with
// 16B-granule pre-swizzle (granule gd stored at gd^c); zero-pad dk>i, i>=50.
__global__ __launch_bounds__(256) void k0_wsplit(
        const float* __restrict__ w, _Float16* __restrict__ whl) {
    int dk = blockIdx.x, i = blockIdx.y;
    int t = threadIdx.x;
    int c = t >> 4, gd = t & 15;
    int h = c & 7;
    bool live = (i < 50) && (dk <= i);
    const float* src = w + (((size_t)i * NH + h) * L_ + dk) * D_ + gd * 8;
    h8 o;
    #pragma unroll
    for (int e = 0; e < 8; ++e) {
        float wv = live ? src[e] : 0.f;
        _Float16 hi = (_Float16)wv;
        o[e] = (c < 8) ? hi : (_Float16)((wv - (float)hi) * 1024.f);
    }
    *(h8*)(whl + (((size_t)i * 50 + dk) * 16 + c) * 128 + ((gd ^ c) & 15) * 8) = o;
}

// K1: embedding + LayerNorm + LIF(T=4) -> s16 [T*B][L][D] fp16 PRE-SWIZZLED, smean fp32
__global__ __launch_bounds__(128) void k1_embed_ln_lif(
        const int* __restrict__ item, const float* __restrict__ tab,
        const float* __restrict__ g, const float* __restrict__ be,
        _Float16* __restrict__ s16, float* __restrict__ smean) {
    int bid = blockIdx.x;
    int b = bid / L_, l = bid % L_;
    int d = threadIdx.x;
    int wid = d >> 6, lane = d & 63;
    __shared__ float red[2];
    int it = item[b * L_ + l];
    float e = tab[(size_t)it * D_ + d];
    float sm_ = waveSum(e);
    if (lane == 0) red[wid] = sm_;
    __syncthreads();
    float mu = (red[0] + red[1]) * (1.f / 128.f);
    __syncthreads();
    float df = e - mu;
    float s2 = waveSum(df * df);
    if (lane == 0) red[wid] = s2;
    __syncthreads();
    float var = (red[0] + red[1]) * (1.f / 128.f);
    float x = df / sqrtf(var + EPSF) * g[d] + be[d];
    float v = 0.f, acc = 0.f;
    int pos = (((d >> 3) ^ l) & 15) * 8 + (d & 7);   // pre-swizzled slot
    #pragma unroll
    for (int t = 0; t < T_; ++t) {
        v += (x - v) * 0.5f;
        float sp = (v >= 1.f) ? 1.f : 0.f;
        v *= (1.f - sp);
        s16[((size_t)(t * B_ + b) * L_ + l) * D_ + pos] = (_Float16)sp;
        acc += sp;
    }
    smean[((size_t)b * L_ + l) * D_ + d] = acc * 0.25f;
}

// ---- K2q: grid-packed scale-group conv, B staged in LDS.
// 512 threads = 8 waves, 4 tb/block, LDS 67584 -> 2 blocks/CU (4 waves/SIMD).
// Wave = (tq: tb-pair, dc slice). acc[4 sc][2 tt][MTG jt] (0.5 LDS-reads/MFMA).
// B: single 16KB LDS slot (4 sc x 4KB/dk), reg-staged issue-early/write-late,
// 2 barriers/dk; barrier stalls overlap across the 2 resident blocks.
// dc-partials merged through the dead B-slot after the dk-loop.
// mode 0 (MTG=2): y<2 -> (g0, joff=2y); else (g=y-1, joff=0)   [10 jobs]
// mode 1 (MTG=1): (g=y+1, joff=2)                              [4 jobs]
template<int MTG>
__global__ __launch_bounds__(512, 4) void k2q(
        const _Float16* __restrict__ s16, const _Float16* __restrict__ whl,
        float* __restrict__ y, int mode) {
    extern __shared__ __align__(16) char lds[];
    char* Bslot = lds + 51200;
    const int tbq = blockIdx.x;              // 4 tb per block
    int grp, joff;
    if (mode == 0) {
        if (blockIdx.y < 2) { grp = 0; joff = 2 * blockIdx.y; }
        else { grp = blockIdx.y - 1; joff = 0; }
    } else { grp = blockIdx.y + 1; joff = 2; }
    const int i0 = grp * 4;
    const int kmax = (i0 + 4 <= 50) ? (i0 + 4) : 50;
    const int tid = threadIdx.x;
    const int wave = tid >> 6, lane = tid & 63;
    const int tq = wave >> 2;                // tb-pair 0/1
    const int dc = wave & 3;                 // dc slice 0..3
    const int c_ = lane & 15, g = lane >> 4;

    // stage A: 4 tb x 12800 B (linear copy; swizzle baked into s16)
    {
        const float4* src = (const float4*)(s16 + (size_t)tbq * 4 * (L_ * D_));
        float4* dst = (float4*)lds;
        for (int idx = tid; idx < 3200; idx += 512) dst[idx] = src[idx];
    }
    // B: reg-staged single slot. Thread owns bytes [o0,o0+16) and [o1,o1+16)
    // of the 16KB dk-chunk (4 scales x 4KB, scale-major).
    const char* bsrc = (const char*)whl + (size_t)i0 * 204800;   // 204800 = 50*4096
    const int o0 = tid * 16, o1 = 8192 + tid * 16;
    const char* g0p = bsrc + (size_t)(o0 >> 12) * 204800 + (o0 & 4095);
    const char* g1p = bsrc + (size_t)(o1 >> 12) * 204800 + (o1 & 4095);
    float4 n0 = *(const float4*)(g0p);
    float4 n1 = *(const float4*)(g1p);
    __syncthreads();                         // A staged
    *(float4*)(Bslot + o0) = n0;
    *(float4*)(Bslot + o1) = n1;
    __syncthreads();                         // slot ready (dk=0)

    f4 acc[4][2][MTG];
    #pragma unroll
    for (int sc = 0; sc < 4; ++sc)
        #pragma unroll
        for (int tt = 0; tt < 2; ++tt)
            #pragma unroll
            for (int jt = 0; jt < MTG; ++jt) { f4 z = {0.f, 0.f, 0.f, 0.f}; acc[sc][tt][jt] = z; }

    const int boffc = c_ * 256 + ((((dc << 2) + g) ^ c_) & 15) * 16;
    for (int dk = 0; dk < kmax; ++dk) {
        const bool more = (dk + 1 < kmax);
        float4 m0, m1;
        if (more) {                          // issue next-dk B loads early (T14)
            m0 = *(const float4*)(g0p + (size_t)(dk + 1) * 4096);
            m1 = *(const float4*)(g1p + (size_t)(dk + 1) * 4096);
        }
        __builtin_amdgcn_sched_barrier(0);
        h8 bf[4];
        #pragma unroll
        for (int sc = 0; sc < 4; ++sc)
            bf[sc] = *(const h8*)(Bslot + sc * 4096 + boffc);
        #pragma unroll
        for (int tt = 0; tt < 2; ++tt) {
            const int tbL = tq * 2 + tt;
            #pragma unroll
            for (int jt = 0; jt < MTG; ++jt) {
                int l = (joff + jt) * 16 + c_ + dk; if (l > 49) l = 49;  // fires only where w==0
                h8 a = *(const h8*)(lds + tbL * 12800 + l * 256 +
                                    ((((dc << 2) + g) ^ l) & 15) * 16);
                acc[0][tt][jt] = __builtin_amdgcn_mfma_f32_16x16x32_f16(a, bf[0], acc[0][tt][jt], 0, 0, 0);
                acc[1][tt][jt] = __builtin_amdgcn_mfma_f32_16x16x32_f16(a, bf[1], acc[1][tt][jt], 0, 0, 0);
                acc[2][tt][jt] = __builtin_amdgcn_mfma_f32_16x16x32_f16(a, bf[2], acc[2][tt][jt], 0, 0, 0);
                acc[3][tt][jt] = __builtin_amdgcn_mfma_f32_16x16x32_f16(a, bf[3], acc[3][tt][jt], 0, 0, 0);
            }
        }
        __syncthreads();                     // reads of slot done
        if (more) {
            *(float4*)(Bslot + o0) = m0;
            *(float4*)(Bslot + o1) = m1;
        }
        __syncthreads();                     // slot ready (dk+1)
    }

    // merge dc=1..3 partials into dc=0 through the dead B-slot.
    // per (jt, sc) round: rows ((dc-1)*2+tq)*2+tt in [0,12); 12x64x16B = 12KB <= 16KB.
    f4* mbuf = (f4*)Bslot;
    #pragma unroll
    for (int jt = 0; jt < MTG; ++jt) {
        #pragma unroll
        for (int sc = 0; sc < 4; ++sc) {
            __syncthreads();
            if (dc != 0) {
                f4* wp = mbuf + (size_t)(((dc - 1) * 2 + tq) * 2) * 64 + lane;
                wp[0]  = acc[sc][0][jt];
                wp[64] = acc[sc][1][jt];
            }
            __syncthreads();
            if (dc == 0) {
                #pragma unroll
                for (int dd = 0; dd < 3; ++dd) {
                    const f4* rp = mbuf + (size_t)((dd * 2 + tq) * 2) * 64 + lane;
                    acc[sc][0][jt] += rp[0];
                    acc[sc][1][jt] += rp[64];
                }
            }
        }
    }

    if (dc == 0) {
        const bool hiLane = (c_ < 8);
        const int h = c_ & 7;
        #pragma unroll
        for (int sc = 0; sc < 4; ++sc) {
            const int i = i0 + sc;
            const int J = 50 - i;
            if (J <= 0) continue;
            #pragma unroll
            for (int tt = 0; tt < 2; ++tt) {
                const int tb = tbq * 4 + tq * 2 + tt;
                size_t yb = yoff(i) + ((size_t)tb * NH + h) * J;
                #pragma unroll
                for (int jt = 0; jt < MTG; ++jt) {
                    #pragma unroll
                    for (int r = 0; r < 4; ++r) {
                        float lo = __shfl_xor(acc[sc][tt][jt][r], 8, 64);
                        int j = (joff + jt) * 16 + g * 4 + r;
                        if (hiLane && j < J) y[yb + j] = acc[sc][tt][jt][r] + lo * (1.f / 1024.f);
                    }
                }
            }
        }
    }
}

// ---- K2t: tail scales (i>=36), wave box (t=4 tb, s=4 sc, d=1 dc). 8 tb/block.
// LDS: A 102400 + B slot 16KB (reg-staged dbuf) = 118784 -> 1 block/CU.
// K-partials merged across the 4 dc-waves via A-region at the end (A dead: one job/block).
__global__ __launch_bounds__(512, 2) void k2t(
        const _Float16* __restrict__ s16, const _Float16* __restrict__ whl,
        float* __restrict__ y) {
    extern __shared__ __align__(16) char lds[];
    char* Bslot = lds + 102400;
    const int tbo = blockIdx.x;              // 8 tb per block
    const int i0 = 36 + blockIdx.y * 4;      // 36,40,44,48 (scales 50,51 zero-padded)
    const int kmax = (i0 + 4 <= 50) ? (i0 + 4) : 50;
    const int tid = threadIdx.x;
    const int wave = tid >> 6, lane = tid & 63;
    const int tq = wave >> 2;                // tb-quad 0/1
    const int dc = wave & 3;                 // dc slice 0..3
    const int c_ = lane & 15, g = lane >> 4;

    {
        const float4* src = (const float4*)(s16 + (size_t)tbo * 8 * (L_ * D_));
        float4* dst = (float4*)lds;
        for (int idx = tid; idx < 6400; idx += 512) dst[idx] = src[idx];
    }
    const char* bsrc = (const char*)whl + (size_t)i0 * 204800;
    const int o0 = tid * 16, o1 = 8192 + tid * 16;
    const char* g0p = bsrc + (size_t)(o0 >> 12) * 204800 + (o0 & 4095);
    const char* g1p = bsrc + (size_t)(o1 >> 12) * 204800 + (o1 & 4095);
    float4 n0 = *(const float4*)(g0p);
    float4 n1 = *(const float4*)(g1p);
    __syncthreads();
    *(float4*)(Bslot + o0) = n0;
    *(float4*)(Bslot + o1) = n1;
    __syncthreads();

    f4 acc[4][4];                            // [sc][tt]
    #pragma unroll
    for (int sc = 0; sc < 4; ++sc)
        #pragma unroll
        for (int tt = 0; tt < 4; ++tt) { f4 z = {0.f, 0.f, 0.f, 0.f}; acc[sc][tt] = z; }

    const int boffc = c_ * 256 + ((((dc << 2) + g) ^ c_) & 15) * 16;
    for (int dk = 0; dk < kmax; ++dk) {
        const bool more = (dk + 1 < kmax);
        float4 m0, m1;
        if (more) {
            m0 = *(const float4*)(g0p + (size_t)(dk + 1) * 4096);
            m1 = *(const float4*)(g1p + (size_t)(dk + 1) * 4096);
        }
        __builtin_amdgcn_sched_barrier(0);
        h8 bf[4];
        #pragma unroll
        for (int sc = 0; sc < 4; ++sc)
            bf[sc] = *(const h8*)(Bslot + sc * 4096 + boffc);
        int l = c_ + dk; if (l > 49) l = 49;  // fires only where w==0
        const int aoff = l * 256 + ((((dc << 2) + g) ^ l) & 15) * 16;
        #pragma unroll
        for (int tt = 0; tt < 4; ++tt) {
            h8 a = *(const h8*)(lds + (tq * 4 + tt) * 12800 + aoff);
            #pragma unroll
            for (int sc = 0; sc < 4; ++sc)
                acc[sc][tt] = __builtin_amdgcn_mfma_f32_16x16x32_f16(a, bf[sc], acc[sc][tt], 0, 0, 0);
        }
        __syncthreads();
        if (more) {
            *(float4*)(Bslot + o0) = m0;
            *(float4*)(Bslot + o1) = m1;
        }
        __syncthreads();
    }

    // merge K-partials across dc=1..3 into dc=0 (A region dead now).
    f4* mbuf = (f4*)lds;
    if (dc != 0) {
        f4* wp = mbuf + (size_t)(((dc - 1) * 2 + tq) * 16) * 64 + lane;
        #pragma unroll
        for (int sc = 0; sc < 4; ++sc)
            #pragma unroll
            for (int tt = 0; tt < 4; ++tt)
                wp[(sc * 4 + tt) * 64] = acc[sc][tt];
    }
    __syncthreads();
    if (dc == 0) {
        #pragma unroll
        for (int dd = 0; dd < 3; ++dd) {
            const f4* rp = mbuf + (size_t)((dd * 2 + tq) * 16) * 64 + lane;
            #pragma unroll
            for (int sc = 0; sc < 4; ++sc)
                #pragma unroll
                for (int tt = 0; tt < 4; ++tt)
                    acc[sc][tt] += rp[(sc * 4 + tt) * 64];
        }
        const bool hiLane = (c_ < 8);
        const int h = c_ & 7;
        #pragma unroll
        for (int sc = 0; sc < 4; ++sc) {
            const int i = i0 + sc;
            const int J = 50 - i;
            if (J <= 0) continue;
            #pragma unroll
            for (int tt = 0; tt < 4; ++tt) {
                const int tb = tbo * 8 + tq * 4 + tt;
                size_t yb = yoff(i) + ((size_t)tb * NH + h) * J;
                #pragma unroll
                for (int r = 0; r < 4; ++r) {
                    float lo = __shfl_xor(acc[sc][tt][r], 8, 64);
                    int j = g * 4 + r;
                    if (hiLane && j < J) y[yb + j] = acc[sc][tt][r] + lo * (1.f / 1024.f);
                }
            }
        }
    }
}

// K3: BN stats, two stage (partial over 128-tb chunks, then final)
__global__ __launch_bounds__(256) void k3_partial(
        const float* __restrict__ y, float* __restrict__ psum) {
    int ih = blockIdx.x, ck = blockIdx.y;
    int i = ih >> 3, h = ih & 7;
    int J = 50 - i;
    size_t yb = yoff(i);
    int tid = threadIdx.x;
    int grp = tid >> 5, sub = tid & 31;
    float sm = 0.f, ss = 0.f;
    for (int tb = ck * 128 + grp; tb < (ck + 1) * 128; tb += 8) {
        const float* row = y + yb + ((size_t)tb * NH + h) * J;
        for (int j = sub; j < J; j += 32) { float v = row[j]; sm += v; ss += v * v; }
    }
    __shared__ float r1[4], r2[4];
    float a = waveSum(sm), b = waveSum(ss);
    int wid = tid >> 6, lane = tid & 63;
    if (lane == 0) { r1[wid] = a; r2[wid] = b; }
    __syncthreads();
    if (tid == 0) {
        psum[((size_t)ih * 8 + ck) * 2]     = r1[0] + r1[1] + r1[2] + r1[3];
        psum[((size_t)ih * 8 + ck) * 2 + 1] = r2[0] + r2[1] + r2[2] + r2[3];
    }
}

__global__ __launch_bounds__(256) void k3_final(
        const float* __restrict__ psum, const float* __restrict__ bng,
        float* __restrict__ statm, float* __restrict__ stats_) {
    int ih = blockIdx.x * 256 + threadIdx.x;
    if (ih >= 400) return;
    float S = 0.f, Q = 0.f;
    for (int ck = 0; ck < 8; ++ck) {
        S += psum[((size_t)ih * 8 + ck) * 2];
        Q += psum[((size_t)ih * 8 + ck) * 2 + 1];
    }
    int i = ih >> 3;
    float cnt = 1024.f * (float)(50 - i);
    float m = S / cnt;
    float var = Q / cnt - m * m; if (var < 0.f) var = 0.f;
    statm[ih] = m;
    stats_[ih] = bng[ih] / sqrtf(var + EPSF);
}

// K4: BN + LIF over t + max-pool over j -> poolsum [B,400]
__global__ __launch_bounds__(512) void k4_bn_lif_pool(
        const float* __restrict__ y, const float* __restrict__ statm,
        const float* __restrict__ stats_, const float* __restrict__ bnb,
        float* __restrict__ ps) {
    int b = blockIdx.x, i = blockIdx.y, J = L_ - i;
    int h = threadIdx.x >> 6, lane = threadIdx.x & 63;
    int ih = i * NH + h;
    float m = statm[ih], sc = stats_[ih], bb = bnb[ih];
    size_t yb = yoff(i);
    bool valid = lane < J;
    float v = 0.f; int cnt = 0;
    #pragma unroll
    for (int t = 0; t < T_; ++t) {
        int tb = t * B_ + b;
        float yn;
        if (valid) {
            float raw = y[yb + ((size_t)tb * NH + h) * J + lane];
            yn = (raw - m) * sc + bb;
        } else yn = -1e30f;
        v += (yn - v) * 0.5f;
        bool sp = (v >= 1.f);
        if (sp) v = 0.f;
        if (__any(sp)) cnt++;
    }
    if (lane == 0) ps[(size_t)b * 400 + ih] = (float)cnt;
}

// K5: fused heads
__global__ __launch_bounds__(128) void k5_final(
        const float* __restrict__ smean, const float* __restrict__ ps,
        const float* __restrict__ convv, const float* __restrict__ fchw,
        const float* __restrict__ fchb, const float* __restrict__ fcvw,
        const float* __restrict__ fcvb, float* __restrict__ out) {
    __shared__ float sm_l[L_ * D_];
    __shared__ float vm[NV * D_];
    __shared__ float ps_l[400];
    int b = blockIdx.x, tid = threadIdx.x;
    for (int idx = tid; idx < L_ * D_; idx += 128) sm_l[idx] = smean[(size_t)b * (L_ * D_) + idx];
    for (int idx = tid; idx < 400; idx += 128) ps_l[idx] = ps[(size_t)b * 400 + idx];
    __syncthreads();
    int d = tid;
    #pragma unroll
    for (int c = 0; c < NV; ++c) {
        float a = 0.f;
        for (int l = 0; l < L_; ++l) a += convv[c * L_ + l] * sm_l[l * D_ + d];
        vm[c * D_ + d] = a;
    }
    __syncthreads();
    float acc = fchb[d] + fcvb[d];
    float ah = 0.f;
    for (int ih = 0; ih < 400; ++ih) ah += ps_l[ih] * fchw[d * 400 + ih];
    acc += ah * 0.25f;
    float av = 0.f;
    for (int cd = 0; cd < NV * D_; ++cd) av += vm[cd] * fcvw[d * (NV * D_) + cd];
    acc += av;
    out[(size_t)b * D_ + d] = acc;
}

extern "C" void kernel_launch(void* const* d_in, const int* in_sizes, int n_in,
                              void* d_out, int out_size, void* d_ws, size_t ws_size,
                              hipStream_t stream) {
    const int*   item  = (const int*)d_in[0];
    const float* tab   = (const float*)d_in[1];
    const float* lng   = (const float*)d_in[2];
    const float* lnb   = (const float*)d_in[3];
    const float* convv = (const float*)d_in[4];
    const float* convh = (const float*)d_in[5];
    const float* bng   = (const float*)d_in[6];
    const float* bnb   = (const float*)d_in[7];
    const float* fchw  = (const float*)d_in[8];
    const float* fchb  = (const float*)d_in[9];
    const float* fcvw  = (const float*)d_in[10];
    const float* fcvb  = (const float*)d_in[11];
    float* out = (float*)d_out;

    char* ws = (char*)d_ws;
    // layout (bytes):
    // s16    @ 0          13,107,200   fp16 spikes, pre-swizzled granules
    // smean  @ 13107200    6,553,600
    // y      @ 19660800   41,779,200
    // whl    @ 61440000   10,649,600   fp16 hi/lo weights [52][50][16][128], zero-padded
    // statm  @ 72089600        1,600
    // stats_ @ 72091200        1,600
    // ps     @ 72092800      409,600
    // psum   @ 72502400       25,600   -> total 72,528,000
    _Float16* s16  = (_Float16*)(ws);
    float* smean   = (float*)(ws + 13107200LL);
    float* y       = (float*)(ws + 19660800LL);
    _Float16* whl  = (_Float16*)(ws + 61440000LL);
    float* statm   = (float*)(ws + 72089600LL);
    float* stats_  = (float*)(ws + 72091200LL);
    float* ps      = (float*)(ws + 72092800LL);
    float* psum    = (float*)(ws + 72502400LL);

    hipFuncSetAttribute(reinterpret_cast<const void*>(&k2q<2>),
        hipFuncAttributeMaxDynamicSharedMemorySize, 67584);
    hipFuncSetAttribute(reinterpret_cast<const void*>(&k2q<1>),
        hipFuncAttributeMaxDynamicSharedMemorySize, 67584);
    hipFuncSetAttribute(reinterpret_cast<const void*>(&k2t),
        hipFuncAttributeMaxDynamicSharedMemorySize, 118784);

    k0_wsplit<<<dim3(50, 52), 256, 0, stream>>>(convh, whl);
    k1_embed_ln_lif<<<B_ * L_, 128, 0, stream>>>(item, tab, lng, lnb, s16, smean);
    // coverage: mode0 = {g0/j0-31, g0/j32-63, g1-8/j0-31}; mode1 = {g1-4/j32-47};
    // k2t = scales 36-49 (J<=14, j0-15).
    k2q<2><<<dim3(256, 10), 512, 67584, stream>>>(s16, whl, y, 0);
    k2q<1><<<dim3(256, 4), 512, 67584, stream>>>(s16, whl, y, 1);
    k2t<<<dim3(128, 4), 512, 118784, stream>>>(s16, whl, y);
    k3_partial<<<dim3(400, 8), 256, 0, stream>>>(y, psum);
    k3_final<<<dim3(2, 1), 256, 0, stream>>>(psum, bng, statm, stats_);
    k4_bn_lif_pool<<<dim3(B_, L_), 512, 0, stream>>>(y, statm, stats_, bnb, ps);
    k5_final<<<B_, 128, 0, stream>>>(smean, ps, convv, fchw, fchb, fcvw, fcvb, out);
}